// Round 5
// baseline (639.670 us; speedup 1.0000x reference)
//
#include <hip/hip_runtime.h>
#include <math.h>

#define N_NODES 100000
#define NB 256          // partition blocks
#define NP 1024         // buckets (dst >> 7)
#define G 8             // lanes per node in conv gathers

// ================= bucket-path CSR build (no global atomics) =================

__global__ void k_hist(const int* __restrict__ dst, int E, int chunk,
                       int* __restrict__ hist) {
    __shared__ int bin[NP];
    for (int i = threadIdx.x; i < NP; i += 256) bin[i] = 0;
    __syncthreads();
    int beg = blockIdx.x * chunk;
    int end = beg + chunk; if (end > E) end = E;
    for (int e = beg + threadIdx.x; e < end; e += 256)
        atomicAdd(&bin[dst[e] >> 7], 1);
    __syncthreads();
    for (int i = threadIdx.x; i < NP; i += 256)
        hist[blockIdx.x * NP + i] = bin[i];
}

__global__ void k_s1(const int* __restrict__ hist, int* __restrict__ base) {
    __shared__ int sh[NP];
    int b = threadIdx.x;
    int s = 0;
    #pragma unroll 8
    for (int k = 0; k < NB; ++k) s += hist[k * NP + b];
    sh[b] = s;
    __syncthreads();
    for (int off = 1; off < NP; off <<= 1) {
        int u = (b >= off) ? sh[b - off] : 0;
        __syncthreads();
        sh[b] += u;
        __syncthreads();
    }
    base[b] = sh[b] - s;
    if (b == NP - 1) base[NP] = sh[b];
}

__global__ void k_s2(int* __restrict__ hist, const int* __restrict__ base) {
    __shared__ int sh[NB];
    int b = blockIdx.x, t = threadIdx.x;
    int v = hist[t * NP + b];
    sh[t] = v;
    __syncthreads();
    for (int off = 1; off < NB; off <<= 1) {
        int u = (t >= off) ? sh[t - off] : 0;
        __syncthreads();
        sh[t] += u;
        __syncthreads();
    }
    hist[t * NP + b] = base[b] + sh[t] - v;
}

__global__ void k_part(const int* __restrict__ src, const int* __restrict__ dst,
                       int E, int chunk, const int* __restrict__ hist,
                       unsigned int* __restrict__ part) {
    __shared__ int cur[NP];
    for (int i = threadIdx.x; i < NP; i += 256)
        cur[i] = hist[blockIdx.x * NP + i];
    __syncthreads();
    int beg = blockIdx.x * chunk;
    int end = beg + chunk; if (end > E) end = E;
    for (int e = beg + threadIdx.x; e < end; e += 256) {
        int d = dst[e];
        int p = atomicAdd(&cur[d >> 7], 1);
        part[p] = ((unsigned)src[e] << 7) | (unsigned)(d & 127);
    }
}

// per-bucket: deg -> offs; prescaled xp4 (w = dinv); local scatter -> col
__global__ void k_csr(const unsigned int* __restrict__ part, const int* __restrict__ base,
                      const float* __restrict__ x,
                      int* __restrict__ offs,
                      float4* __restrict__ xp4, int* __restrict__ col, int N) {
    __shared__ int cnt[128];
    __shared__ int scn[128];
    __shared__ int cur[128];
    int b = blockIdx.x, t = threadIdx.x;
    int lo = base[b], hi = base[b + 1];
    if (t < 128) cnt[t] = 0;
    __syncthreads();
    for (int e = lo + t; e < hi; e += 256)
        atomicAdd(&cnt[part[e] & 127u], 1);
    __syncthreads();
    int v = (t < 128) ? cnt[t] : 0;
    if (t < 128) scn[t] = v;
    __syncthreads();
    for (int off = 1; off < 128; off <<= 1) {
        int u = (t < 128 && t >= off) ? scn[t - off] : 0;
        __syncthreads();
        if (t < 128) scn[t] += u;
        __syncthreads();
    }
    if (t < 128) {
        int pos = lo + scn[t] - v;
        cur[t] = pos;
        int g = (b << 7) + t;
        if (g < N) {
            offs[g] = pos;
            float di = rsqrtf((float)(v + 1));   // +1 self-loop
            xp4[g] = make_float4(x[3*g] * di, x[3*g+1] * di, x[3*g+2] * di, di);
        }
    }
    if (b == 0 && t == 0) offs[N] = base[(N_NODES + 127) >> 7];
    __syncthreads();
    for (int e = lo + t; e < hi; e += 256) {
        unsigned int w = part[e];
        int p = atomicAdd(&cur[w & 127u], 1);
        col[p] = (int)(w >> 7);
    }
}

// ================= fallback CSR build (global atomics) ==========

__global__ void k_deg(const int* __restrict__ dst, int E, int* __restrict__ deg) {
    int e = blockIdx.x * blockDim.x + threadIdx.x;
    if (e < E) atomicAdd(&deg[dst[e]], 1);
}

__global__ void k_scan1(const int* __restrict__ deg, int* __restrict__ offs,
                        int* __restrict__ partl, int N) {
    __shared__ int sh[256];
    int i = blockIdx.x * 256 + threadIdx.x;
    int t = threadIdx.x;
    int v = (i < N) ? deg[i] : 0;
    sh[t] = v;
    __syncthreads();
    #pragma unroll
    for (int off = 1; off < 256; off <<= 1) {
        int u = (t >= off) ? sh[t - off] : 0;
        __syncthreads();
        sh[t] += u;
        __syncthreads();
    }
    if (i < N) offs[i] = sh[t] - v;
    if (t == 255) partl[blockIdx.x] = sh[255];
}

__global__ void k_scan2(int* __restrict__ partl, int* __restrict__ offs, int nb, int N) {
    __shared__ int sh[1024];
    int t = threadIdx.x;
    int v = (t < nb) ? partl[t] : 0;
    sh[t] = v;
    __syncthreads();
    #pragma unroll
    for (int off = 1; off < 1024; off <<= 1) {
        int u = (t >= off) ? sh[t - off] : 0;
        __syncthreads();
        sh[t] += u;
        __syncthreads();
    }
    if (t < nb) partl[t] = sh[t] - v;
    if (t == 1023) offs[N] = sh[1023];
}

__global__ void k_scan3(int* __restrict__ offs, const int* __restrict__ partl, int N) {
    int i = blockIdx.x * 256 + threadIdx.x;
    if (i < N) offs[i] += partl[blockIdx.x];
}

__global__ void k_fill_cur(const int* __restrict__ src, const int* __restrict__ dst,
                           const int* __restrict__ offs, int* __restrict__ cur,
                           int* __restrict__ col, int E) {
    int e = blockIdx.x * blockDim.x + threadIdx.x;
    if (e >= E) return;
    int d = dst[e];
    col[offs[d] + atomicAdd(&cur[d], 1)] = src[e];
}

__global__ void k_prescale(const float* __restrict__ x, const int* __restrict__ offs,
                           float4* __restrict__ xp4, int N) {
    int i = blockIdx.x * blockDim.x + threadIdx.x;
    if (i >= N) return;
    int d = offs[i+1] - offs[i];
    float di = rsqrtf((float)(d + 1));
    xp4[i] = make_float4(x[3*i] * di, x[3*i+1] * di, x[3*i+2] * di, di);
}

// ================= convs: G lanes per node, float4 gathers =================

__global__ void k_conv1(const int* __restrict__ offs, const int* __restrict__ col,
                        const float4* __restrict__ xp4,
                        const float* __restrict__ W1, const float* __restrict__ b1,
                        const float* __restrict__ W2,
                        float4* __restrict__ h2p4, int N) {
    int tid = blockIdx.x * blockDim.x + threadIdx.x;
    int i = tid >> 3, g = tid & (G - 1);
    if (i >= N) return;
    float s0 = 0.f, s1 = 0.f, s2 = 0.f, di = 0.f;
    if (g == 0) {
        float4 self = xp4[i];          // self-loop term (already * di)
        s0 = self.x; s1 = self.y; s2 = self.z; di = self.w;
    }
    int beg = offs[i], end = offs[i+1];
    for (int k = beg + g; k < end; k += G) {
        float4 v = xp4[col[k]];
        s0 += v.x; s1 += v.y; s2 += v.z;
    }
    #pragma unroll
    for (int off = G/2; off > 0; off >>= 1) {
        s0 += __shfl_down(s0, off, G);
        s1 += __shfl_down(s1, off, G);
        s2 += __shfl_down(s2, off, G);
    }
    if (g == 0) {
        float g0 = s0 * di, g1 = s1 * di, g2 = s2 * di;   // (Âx)[i]
        float o0 = 0.f, o1 = 0.f, o2 = 0.f;
        #pragma unroll
        for (int j = 0; j < 16; ++j) {
            float t = fmaxf(g0 * W1[j] + g1 * W1[16 + j] + g2 * W1[32 + j] + b1[j], 0.f);
            o0 += t * W2[3*j + 0];
            o1 += t * W2[3*j + 1];
            o2 += t * W2[3*j + 2];
        }
        h2p4[i] = make_float4(o0 * di, o1 * di, o2 * di, di);
    }
}

__global__ void k_conv2(const int* __restrict__ offs, const int* __restrict__ col,
                        const float4* __restrict__ h2p4,
                        const float* __restrict__ b2, const float* __restrict__ W3,
                        float* __restrict__ embed_out, float4* __restrict__ h3p4, int N) {
    int tid = blockIdx.x * blockDim.x + threadIdx.x;
    int i = tid >> 3, g = tid & (G - 1);
    if (i >= N) return;
    float s0 = 0.f, s1 = 0.f, s2 = 0.f, di = 0.f;
    if (g == 0) {
        float4 self = h2p4[i];
        s0 = self.x; s1 = self.y; s2 = self.z; di = self.w;
    }
    int beg = offs[i], end = offs[i+1];
    for (int k = beg + g; k < end; k += G) {
        float4 v = h2p4[col[k]];
        s0 += v.x; s1 += v.y; s2 += v.z;
    }
    #pragma unroll
    for (int off = G/2; off > 0; off >>= 1) {
        s0 += __shfl_down(s0, off, G);
        s1 += __shfl_down(s1, off, G);
        s2 += __shfl_down(s2, off, G);
    }
    if (g == 0) {
        float t0 = s0 * di + b2[0];
        float t1 = s1 * di + b2[1];
        float t2 = s2 * di + b2[2];
        float inv = 1.0f / fmaxf(sqrtf(t0*t0 + t1*t1 + t2*t2), 1e-12f);
        float e0 = t0*inv, e1 = t1*inv, e2 = t2*inv;
        embed_out[3*i] = e0; embed_out[3*i+1] = e1; embed_out[3*i+2] = e2;
        h3p4[i] = make_float4((e0*W3[0] + e1*W3[3] + e2*W3[6]) * di,
                              (e0*W3[1] + e1*W3[4] + e2*W3[7]) * di,
                              (e0*W3[2] + e1*W3[5] + e2*W3[8]) * di, di);
    }
}

__global__ void k_conv3(const int* __restrict__ offs, const int* __restrict__ col,
                        const float4* __restrict__ h3p4,
                        const float* __restrict__ b3, const float* __restrict__ Wp,
                        const float* __restrict__ bp,
                        float* __restrict__ hout, float* __restrict__ gsum, int N) {
    int tid = blockIdx.x * blockDim.x + threadIdx.x;
    int i = tid >> 3, g = tid & (G - 1);
    float p0 = 0.f, p1 = 0.f, p2 = 0.f;
    if (i < N) {
        float s0 = 0.f, s1 = 0.f, s2 = 0.f, di = 0.f;
        if (g == 0) {
            float4 self = h3p4[i];
            s0 = self.x; s1 = self.y; s2 = self.z; di = self.w;
        }
        int beg = offs[i], end = offs[i+1];
        for (int k = beg + g; k < end; k += G) {
            float4 v = h3p4[col[k]];
            s0 += v.x; s1 += v.y; s2 += v.z;
        }
        #pragma unroll
        for (int off = G/2; off > 0; off >>= 1) {
            s0 += __shfl_down(s0, off, G);
            s1 += __shfl_down(s1, off, G);
            s2 += __shfl_down(s2, off, G);
        }
        if (g == 0) {
            float t0 = s0 * di + b3[0];
            float t1 = s1 * di + b3[1];
            float t2 = s2 * di + b3[2];
            p0 = t0*Wp[0] + t1*Wp[3] + t2*Wp[6] + bp[0];
            p1 = t0*Wp[1] + t1*Wp[4] + t2*Wp[7] + bp[1];
            p2 = t0*Wp[2] + t1*Wp[5] + t2*Wp[8] + bp[2];
            hout[3*i] = p0; hout[3*i+1] = p1; hout[3*i+2] = p2;
        }
    }
    // pooled sum: only g==0 lanes hold values, rest are 0
    #pragma unroll
    for (int off = 32; off > 0; off >>= 1) {
        p0 += __shfl_down(p0, off);
        p1 += __shfl_down(p1, off);
        p2 += __shfl_down(p2, off);
    }
    if ((threadIdx.x & 63) == 0) {
        atomicAdd(&gsum[0], p0);
        atomicAdd(&gsum[1], p1);
        atomicAdd(&gsum[2], p2);
    }
}

__global__ void k_head(const float* __restrict__ gsum, const float* __restrict__ Wl,
                       const float* __restrict__ bl, float* __restrict__ out, int N) {
    if (blockIdx.x != 0 || threadIdx.x != 0) return;
    float p0 = gsum[0] / (float)N, p1 = gsum[1] / (float)N, p2 = gsum[2] / (float)N;
    float l[10];
    float m = -1e30f;
    #pragma unroll
    for (int j = 0; j < 10; ++j) {
        l[j] = p0 * Wl[j] + p1 * Wl[10 + j] + p2 * Wl[20 + j] + bl[j];
        m = fmaxf(m, l[j]);
    }
    float s = 0.f;
    #pragma unroll
    for (int j = 0; j < 10; ++j) s += expf(l[j] - m);
    float lse = logf(s) + m;
    #pragma unroll
    for (int j = 0; j < 10; ++j) out[j] = l[j] - lse;
}

extern "C" void kernel_launch(void* const* d_in, const int* in_sizes, int n_in,
                              void* d_out, int out_size, void* d_ws, size_t ws_size,
                              hipStream_t stream) {
    const int N = N_NODES;
    const float* x  = (const float*)d_in[0];
    const int*   ei = (const int*)d_in[1];
    const int    E  = in_sizes[1] / 2;
    const int* src = ei;
    const int* dst = ei + E;
    const float* W1 = (const float*)d_in[2];
    const float* b1 = (const float*)d_in[3];
    const float* W2 = (const float*)d_in[4];
    const float* b2 = (const float*)d_in[5];
    const float* W3 = (const float*)d_in[6];
    const float* b3 = (const float*)d_in[7];
    const float* Wp = (const float*)d_in[8];
    const float* bp = (const float*)d_in[9];
    const float* Wl = (const float*)d_in[10];
    const float* bl = (const float*)d_in[11];

    float* out     = (float*)d_out;
    float* h_out   = out + 10;              // [N,3]
    float* emb_out = out + 10 + 3 * N;      // [N,3]

    const int B = 256;
    int gE = (E + B - 1) / B;
    int gN = (N + B - 1) / B;
    int gC = ((size_t)N * G + B - 1) / B;   // conv grid: G lanes per node
    int chunk = (E + NB - 1) / NB;
    int PB = (N + 127) >> 7;

    char* Wm = (char*)d_ws;

    // ---- bucket-path layout ----
    size_t off = 0;
    auto alloc = [&](size_t elems) { void* p = Wm + off; off += elems * 4; return p; };
    int*          col  = (int*)alloc((size_t)E);
    unsigned int* part = (unsigned int*)alloc((size_t)E);
    int*          hist = (int*)alloc((size_t)NB * NP);
    int*          base = (int*)alloc(NP + 1);
    int*          offs = (int*)alloc(N + 1);
    float4*       bufA = (float4*)alloc(4 * N);
    float4*       bufB = (float4*)alloc(4 * N);
    float*        gsum = (float*)alloc(4);
    size_t need_bucket = off;

    if (ws_size >= need_bucket) {
        hipMemsetAsync(gsum, 0, 4 * sizeof(float), stream);
        k_hist<<<NB, B, 0, stream>>>(dst, E, chunk, hist);
        k_s1<<<1, NP, 0, stream>>>(hist, base);
        k_s2<<<NP, NB, 0, stream>>>(hist, base);
        k_part<<<NB, B, 0, stream>>>(src, dst, E, chunk, hist, part);
        k_csr<<<PB, B, 0, stream>>>(part, base, x, offs, bufA, col, N);
    } else {
        // ---- fallback layout ----
        off = 0;
        col  = (int*)alloc((size_t)E);
        int* deg = (int*)alloc(N);
        offs = (int*)alloc(N + 1);
        bufA = (float4*)alloc(4 * N);
        bufB = (float4*)alloc(4 * N);
        gsum = (float*)alloc(4);
        int* partl = (int*)alloc(1024);
        int* cur = (int*)alloc(N);

        hipMemsetAsync(deg, 0, N * sizeof(int), stream);
        hipMemsetAsync(gsum, 0, 4 * sizeof(float), stream);
        hipMemsetAsync(cur, 0, N * sizeof(int), stream);

        k_deg<<<gE, B, 0, stream>>>(dst, E, deg);
        k_scan1<<<gN, B, 0, stream>>>(deg, offs, partl, N);
        k_scan2<<<1, 1024, 0, stream>>>(partl, offs, gN, N);
        k_scan3<<<gN, B, 0, stream>>>(offs, partl, N);
        k_fill_cur<<<gE, B, 0, stream>>>(src, dst, offs, cur, col, E);
        k_prescale<<<gN, B, 0, stream>>>(x, offs, bufA, N);
    }

    // convs: G lanes/node, float4 gathers, dinv carried in .w
    k_conv1<<<gC, B, 0, stream>>>(offs, col, bufA, W1, b1, W2, bufB, N);
    k_conv2<<<gC, B, 0, stream>>>(offs, col, bufB, b2, W3, emb_out, bufA, N);
    k_conv3<<<gC, B, 0, stream>>>(offs, col, bufA, b3, Wp, bp, h_out, gsum, N);

    k_head<<<1, 64, 0, stream>>>(gsum, Wl, bl, out, N);
}

// Round 6
// 170.744 us; speedup vs baseline: 3.7464x; 3.7464x over previous
//
#include <hip/hip_runtime.h>
#include <math.h>

#define N_NODES 100000
#define NB 256          // partition blocks
#define NP 1024         // buckets (dst >> 7)
#define G 8             // lanes per node in conv gathers

// ================= bucket-path CSR build (no global atomics) =================

__global__ void k_hist(const int* __restrict__ dst, int E, int chunk,
                       int* __restrict__ hist) {
    __shared__ int bin[NP];
    for (int i = threadIdx.x; i < NP; i += 256) bin[i] = 0;
    __syncthreads();
    int beg = blockIdx.x * chunk;
    int end = beg + chunk; if (end > E) end = E;
    for (int e = beg + threadIdx.x; e < end; e += 256)
        atomicAdd(&bin[dst[e] >> 7], 1);
    __syncthreads();
    for (int i = threadIdx.x; i < NP; i += 256)
        hist[blockIdx.x * NP + i] = bin[i];
}

__global__ void k_s1(const int* __restrict__ hist, int* __restrict__ base) {
    __shared__ int sh[NP];
    int b = threadIdx.x;
    int s = 0;
    #pragma unroll 8
    for (int k = 0; k < NB; ++k) s += hist[k * NP + b];
    sh[b] = s;
    __syncthreads();
    for (int off = 1; off < NP; off <<= 1) {
        int u = (b >= off) ? sh[b - off] : 0;
        __syncthreads();
        sh[b] += u;
        __syncthreads();
    }
    base[b] = sh[b] - s;
    if (b == NP - 1) base[NP] = sh[b];
}

__global__ void k_s2(int* __restrict__ hist, const int* __restrict__ base) {
    __shared__ int sh[NB];
    int b = blockIdx.x, t = threadIdx.x;
    int v = hist[t * NP + b];
    sh[t] = v;
    __syncthreads();
    for (int off = 1; off < NB; off <<= 1) {
        int u = (t >= off) ? sh[t - off] : 0;
        __syncthreads();
        sh[t] += u;
        __syncthreads();
    }
    hist[t * NP + b] = base[b] + sh[t] - v;
}

__global__ void k_part(const int* __restrict__ src, const int* __restrict__ dst,
                       int E, int chunk, const int* __restrict__ hist,
                       unsigned int* __restrict__ part) {
    __shared__ int cur[NP];
    for (int i = threadIdx.x; i < NP; i += 256)
        cur[i] = hist[blockIdx.x * NP + i];
    __syncthreads();
    int beg = blockIdx.x * chunk;
    int end = beg + chunk; if (end > E) end = E;
    for (int e = beg + threadIdx.x; e < end; e += 256) {
        int d = dst[e];
        int p = atomicAdd(&cur[d >> 7], 1);
        part[p] = ((unsigned)src[e] << 7) | (unsigned)(d & 127);
    }
}

// per-bucket: deg -> offs; prescaled xp4 (w = dinv); local scatter -> col
__global__ void k_csr(const unsigned int* __restrict__ part, const int* __restrict__ base,
                      const float* __restrict__ x,
                      int* __restrict__ offs,
                      float4* __restrict__ xp4, int* __restrict__ col, int N) {
    __shared__ int cnt[128];
    __shared__ int scn[128];
    __shared__ int cur[128];
    int b = blockIdx.x, t = threadIdx.x;
    int lo = base[b], hi = base[b + 1];
    if (t < 128) cnt[t] = 0;
    __syncthreads();
    for (int e = lo + t; e < hi; e += 256)
        atomicAdd(&cnt[part[e] & 127u], 1);
    __syncthreads();
    int v = (t < 128) ? cnt[t] : 0;
    if (t < 128) scn[t] = v;
    __syncthreads();
    for (int off = 1; off < 128; off <<= 1) {
        int u = (t < 128 && t >= off) ? scn[t - off] : 0;
        __syncthreads();
        if (t < 128) scn[t] += u;
        __syncthreads();
    }
    if (t < 128) {
        int pos = lo + scn[t] - v;
        cur[t] = pos;
        int g = (b << 7) + t;
        if (g < N) {
            offs[g] = pos;
            float di = rsqrtf((float)(v + 1));   // +1 self-loop
            xp4[g] = make_float4(x[3*g] * di, x[3*g+1] * di, x[3*g+2] * di, di);
        }
    }
    if (b == 0 && t == 0) offs[N] = base[(N_NODES + 127) >> 7];
    __syncthreads();
    for (int e = lo + t; e < hi; e += 256) {
        unsigned int w = part[e];
        int p = atomicAdd(&cur[w & 127u], 1);
        col[p] = (int)(w >> 7);
    }
}

// ================= fallback CSR build (global atomics) ==========

__global__ void k_deg(const int* __restrict__ dst, int E, int* __restrict__ deg) {
    int e = blockIdx.x * blockDim.x + threadIdx.x;
    if (e < E) atomicAdd(&deg[dst[e]], 1);
}

__global__ void k_scan1(const int* __restrict__ deg, int* __restrict__ offs,
                        int* __restrict__ partl, int N) {
    __shared__ int sh[256];
    int i = blockIdx.x * 256 + threadIdx.x;
    int t = threadIdx.x;
    int v = (i < N) ? deg[i] : 0;
    sh[t] = v;
    __syncthreads();
    #pragma unroll
    for (int off = 1; off < 256; off <<= 1) {
        int u = (t >= off) ? sh[t - off] : 0;
        __syncthreads();
        sh[t] += u;
        __syncthreads();
    }
    if (i < N) offs[i] = sh[t] - v;
    if (t == 255) partl[blockIdx.x] = sh[255];
}

__global__ void k_scan2(int* __restrict__ partl, int* __restrict__ offs, int nb, int N) {
    __shared__ int sh[1024];
    int t = threadIdx.x;
    int v = (t < nb) ? partl[t] : 0;
    sh[t] = v;
    __syncthreads();
    #pragma unroll
    for (int off = 1; off < 1024; off <<= 1) {
        int u = (t >= off) ? sh[t - off] : 0;
        __syncthreads();
        sh[t] += u;
        __syncthreads();
    }
    if (t < nb) partl[t] = sh[t] - v;
    if (t == 1023) offs[N] = sh[1023];
}

__global__ void k_scan3(int* __restrict__ offs, const int* __restrict__ partl, int N) {
    int i = blockIdx.x * 256 + threadIdx.x;
    if (i < N) offs[i] += partl[blockIdx.x];
}

__global__ void k_fill_cur(const int* __restrict__ src, const int* __restrict__ dst,
                           const int* __restrict__ offs, int* __restrict__ cur,
                           int* __restrict__ col, int E) {
    int e = blockIdx.x * blockDim.x + threadIdx.x;
    if (e >= E) return;
    int d = dst[e];
    col[offs[d] + atomicAdd(&cur[d], 1)] = src[e];
}

__global__ void k_prescale(const float* __restrict__ x, const int* __restrict__ offs,
                           float4* __restrict__ xp4, int N) {
    int i = blockIdx.x * blockDim.x + threadIdx.x;
    if (i >= N) return;
    int d = offs[i+1] - offs[i];
    float di = rsqrtf((float)(d + 1));
    xp4[i] = make_float4(x[3*i] * di, x[3*i+1] * di, x[3*i+2] * di, di);
}

// ================= convs: G lanes per node, float4 gathers =================

__global__ void k_conv1(const int* __restrict__ offs, const int* __restrict__ col,
                        const float4* __restrict__ xp4,
                        const float* __restrict__ W1, const float* __restrict__ b1,
                        const float* __restrict__ W2,
                        float4* __restrict__ h2p4, int N) {
    int tid = blockIdx.x * blockDim.x + threadIdx.x;
    int i = tid >> 3, g = tid & (G - 1);
    if (i >= N) return;
    float s0 = 0.f, s1 = 0.f, s2 = 0.f, di = 0.f;
    if (g == 0) {
        float4 self = xp4[i];          // self-loop term (already * di)
        s0 = self.x; s1 = self.y; s2 = self.z; di = self.w;
    }
    int beg = offs[i], end = offs[i+1];
    for (int k = beg + g; k < end; k += G) {
        float4 v = xp4[col[k]];
        s0 += v.x; s1 += v.y; s2 += v.z;
    }
    #pragma unroll
    for (int off = G/2; off > 0; off >>= 1) {
        s0 += __shfl_down(s0, off, G);
        s1 += __shfl_down(s1, off, G);
        s2 += __shfl_down(s2, off, G);
    }
    if (g == 0) {
        float g0 = s0 * di, g1 = s1 * di, g2 = s2 * di;   // (Âx)[i]
        float o0 = 0.f, o1 = 0.f, o2 = 0.f;
        #pragma unroll
        for (int j = 0; j < 16; ++j) {
            float t = fmaxf(g0 * W1[j] + g1 * W1[16 + j] + g2 * W1[32 + j] + b1[j], 0.f);
            o0 += t * W2[3*j + 0];
            o1 += t * W2[3*j + 1];
            o2 += t * W2[3*j + 2];
        }
        h2p4[i] = make_float4(o0 * di, o1 * di, o2 * di, di);
    }
}

__global__ void k_conv2(const int* __restrict__ offs, const int* __restrict__ col,
                        const float4* __restrict__ h2p4,
                        const float* __restrict__ b2, const float* __restrict__ W3,
                        float* __restrict__ embed_out, float4* __restrict__ h3p4, int N) {
    int tid = blockIdx.x * blockDim.x + threadIdx.x;
    int i = tid >> 3, g = tid & (G - 1);
    if (i >= N) return;
    float s0 = 0.f, s1 = 0.f, s2 = 0.f, di = 0.f;
    if (g == 0) {
        float4 self = h2p4[i];
        s0 = self.x; s1 = self.y; s2 = self.z; di = self.w;
    }
    int beg = offs[i], end = offs[i+1];
    for (int k = beg + g; k < end; k += G) {
        float4 v = h2p4[col[k]];
        s0 += v.x; s1 += v.y; s2 += v.z;
    }
    #pragma unroll
    for (int off = G/2; off > 0; off >>= 1) {
        s0 += __shfl_down(s0, off, G);
        s1 += __shfl_down(s1, off, G);
        s2 += __shfl_down(s2, off, G);
    }
    if (g == 0) {
        float t0 = s0 * di + b2[0];
        float t1 = s1 * di + b2[1];
        float t2 = s2 * di + b2[2];
        float inv = 1.0f / fmaxf(sqrtf(t0*t0 + t1*t1 + t2*t2), 1e-12f);
        float e0 = t0*inv, e1 = t1*inv, e2 = t2*inv;
        embed_out[3*i] = e0; embed_out[3*i+1] = e1; embed_out[3*i+2] = e2;
        h3p4[i] = make_float4((e0*W3[0] + e1*W3[3] + e2*W3[6]) * di,
                              (e0*W3[1] + e1*W3[4] + e2*W3[7]) * di,
                              (e0*W3[2] + e1*W3[5] + e2*W3[8]) * di, di);
    }
}

// conv3: no global atomics — block partial sums to pool[blockIdx]
__global__ void k_conv3(const int* __restrict__ offs, const int* __restrict__ col,
                        const float4* __restrict__ h3p4,
                        const float* __restrict__ b3, const float* __restrict__ Wp,
                        const float* __restrict__ bp,
                        float* __restrict__ hout, float* __restrict__ pool, int N) {
    __shared__ float psum[3];
    if (threadIdx.x == 0) { psum[0] = 0.f; psum[1] = 0.f; psum[2] = 0.f; }
    __syncthreads();
    int tid = blockIdx.x * blockDim.x + threadIdx.x;
    int i = tid >> 3, g = tid & (G - 1);
    float p0 = 0.f, p1 = 0.f, p2 = 0.f;
    if (i < N) {
        float s0 = 0.f, s1 = 0.f, s2 = 0.f, di = 0.f;
        if (g == 0) {
            float4 self = h3p4[i];
            s0 = self.x; s1 = self.y; s2 = self.z; di = self.w;
        }
        int beg = offs[i], end = offs[i+1];
        for (int k = beg + g; k < end; k += G) {
            float4 v = h3p4[col[k]];
            s0 += v.x; s1 += v.y; s2 += v.z;
        }
        #pragma unroll
        for (int off = G/2; off > 0; off >>= 1) {
            s0 += __shfl_down(s0, off, G);
            s1 += __shfl_down(s1, off, G);
            s2 += __shfl_down(s2, off, G);
        }
        if (g == 0) {
            float t0 = s0 * di + b3[0];
            float t1 = s1 * di + b3[1];
            float t2 = s2 * di + b3[2];
            p0 = t0*Wp[0] + t1*Wp[3] + t2*Wp[6] + bp[0];
            p1 = t0*Wp[1] + t1*Wp[4] + t2*Wp[7] + bp[1];
            p2 = t0*Wp[2] + t1*Wp[5] + t2*Wp[8] + bp[2];
            hout[3*i] = p0; hout[3*i+1] = p1; hout[3*i+2] = p2;
        }
    }
    // wave reduce (only g==0 lanes nonzero), then LDS atomic per wave, then one store
    #pragma unroll
    for (int off = 32; off > 0; off >>= 1) {
        p0 += __shfl_down(p0, off);
        p1 += __shfl_down(p1, off);
        p2 += __shfl_down(p2, off);
    }
    if ((threadIdx.x & 63) == 0) {
        atomicAdd(&psum[0], p0);
        atomicAdd(&psum[1], p1);
        atomicAdd(&psum[2], p2);
    }
    __syncthreads();
    if (threadIdx.x == 0) {
        pool[3*blockIdx.x]   = psum[0];
        pool[3*blockIdx.x+1] = psum[1];
        pool[3*blockIdx.x+2] = psum[2];
    }
}

// head: deterministic reduce of block partials, then logits + log_softmax
__global__ void k_head(const float* __restrict__ pool, int nb,
                       const float* __restrict__ Wl, const float* __restrict__ bl,
                       float* __restrict__ out, int N) {
    __shared__ float sh[12];  // 4 waves x 3
    int t = threadIdx.x;
    float p0 = 0.f, p1 = 0.f, p2 = 0.f;
    for (int k = t; k < nb; k += 256) {
        p0 += pool[3*k]; p1 += pool[3*k+1]; p2 += pool[3*k+2];
    }
    #pragma unroll
    for (int off = 32; off > 0; off >>= 1) {
        p0 += __shfl_down(p0, off);
        p1 += __shfl_down(p1, off);
        p2 += __shfl_down(p2, off);
    }
    if ((t & 63) == 0) {
        int w = t >> 6;
        sh[3*w] = p0; sh[3*w+1] = p1; sh[3*w+2] = p2;
    }
    __syncthreads();
    if (t == 0) {
        p0 = sh[0] + sh[3] + sh[6] + sh[9];
        p1 = sh[1] + sh[4] + sh[7] + sh[10];
        p2 = sh[2] + sh[5] + sh[8] + sh[11];
        p0 /= (float)N; p1 /= (float)N; p2 /= (float)N;
        float l[10];
        float m = -1e30f;
        #pragma unroll
        for (int j = 0; j < 10; ++j) {
            l[j] = p0 * Wl[j] + p1 * Wl[10 + j] + p2 * Wl[20 + j] + bl[j];
            m = fmaxf(m, l[j]);
        }
        float s = 0.f;
        #pragma unroll
        for (int j = 0; j < 10; ++j) s += expf(l[j] - m);
        float lse = logf(s) + m;
        #pragma unroll
        for (int j = 0; j < 10; ++j) out[j] = l[j] - lse;
    }
}

extern "C" void kernel_launch(void* const* d_in, const int* in_sizes, int n_in,
                              void* d_out, int out_size, void* d_ws, size_t ws_size,
                              hipStream_t stream) {
    const int N = N_NODES;
    const float* x  = (const float*)d_in[0];
    const int*   ei = (const int*)d_in[1];
    const int    E  = in_sizes[1] / 2;
    const int* src = ei;
    const int* dst = ei + E;
    const float* W1 = (const float*)d_in[2];
    const float* b1 = (const float*)d_in[3];
    const float* W2 = (const float*)d_in[4];
    const float* b2 = (const float*)d_in[5];
    const float* W3 = (const float*)d_in[6];
    const float* b3 = (const float*)d_in[7];
    const float* Wp = (const float*)d_in[8];
    const float* bp = (const float*)d_in[9];
    const float* Wl = (const float*)d_in[10];
    const float* bl = (const float*)d_in[11];

    float* out     = (float*)d_out;
    float* h_out   = out + 10;              // [N,3]
    float* emb_out = out + 10 + 3 * N;      // [N,3]

    const int B = 256;
    int gE = (E + B - 1) / B;
    int gN = (N + B - 1) / B;
    int gC = ((size_t)N * G + B - 1) / B;   // conv grid: G lanes per node (3125)
    int chunk = (E + NB - 1) / NB;
    int PB = (N + 127) >> 7;

    char* Wm = (char*)d_ws;

    // ---- bucket-path layout ----
    size_t off = 0;
    auto alloc = [&](size_t elems) { void* p = Wm + off; off += elems * 4; return p; };
    int*          col  = (int*)alloc((size_t)E);
    unsigned int* part = (unsigned int*)alloc((size_t)E);
    int*          hist = (int*)alloc((size_t)NB * NP);
    int*          base = (int*)alloc(NP + 1);
    int*          offs = (int*)alloc(N + 1);
    float4*       bufA = (float4*)alloc(4 * N);
    float4*       bufB = (float4*)alloc(4 * N);
    float*        pool = (float*)alloc(3 * (size_t)gC + 4);
    size_t need_bucket = off;

    if (ws_size >= need_bucket) {
        k_hist<<<NB, B, 0, stream>>>(dst, E, chunk, hist);
        k_s1<<<1, NP, 0, stream>>>(hist, base);
        k_s2<<<NP, NB, 0, stream>>>(hist, base);
        k_part<<<NB, B, 0, stream>>>(src, dst, E, chunk, hist, part);
        k_csr<<<PB, B, 0, stream>>>(part, base, x, offs, bufA, col, N);
    } else {
        // ---- fallback layout ----
        off = 0;
        col  = (int*)alloc((size_t)E);
        int* deg = (int*)alloc(N);
        offs = (int*)alloc(N + 1);
        bufA = (float4*)alloc(4 * N);
        bufB = (float4*)alloc(4 * N);
        pool = (float*)alloc(3 * (size_t)gC + 4);
        int* partl = (int*)alloc(1024);
        int* cur = (int*)alloc(N);

        hipMemsetAsync(deg, 0, N * sizeof(int), stream);
        hipMemsetAsync(cur, 0, N * sizeof(int), stream);

        k_deg<<<gE, B, 0, stream>>>(dst, E, deg);
        k_scan1<<<gN, B, 0, stream>>>(deg, offs, partl, N);
        k_scan2<<<1, 1024, 0, stream>>>(partl, offs, gN, N);
        k_scan3<<<gN, B, 0, stream>>>(offs, partl, N);
        k_fill_cur<<<gE, B, 0, stream>>>(src, dst, offs, cur, col, E);
        k_prescale<<<gN, B, 0, stream>>>(x, offs, bufA, N);
    }

    // convs: G lanes/node, float4 gathers, dinv carried in .w
    k_conv1<<<gC, B, 0, stream>>>(offs, col, bufA, W1, b1, W2, bufB, N);
    k_conv2<<<gC, B, 0, stream>>>(offs, col, bufB, b2, W3, emb_out, bufA, N);
    k_conv3<<<gC, B, 0, stream>>>(offs, col, bufA, b3, Wp, bp, h_out, pool, N);

    k_head<<<1, 256, 0, stream>>>(pool, gC, Wl, bl, out, N);
}

// Round 7
// 168.412 us; speedup vs baseline: 3.7983x; 1.0138x over previous
//
#include <hip/hip_runtime.h>
#include <math.h>

#define N_NODES 100000
#define NB 256          // partition blocks
#define NP 256          // buckets (dst >> 9), 512 nodes per bucket
#define BSH 9           // bucket shift
#define BMASK 511u      // node-in-bucket mask
#define G 8             // lanes per node in conv gathers

// ================= bucket-path CSR build (no global atomics) =================

__global__ void k_hist(const int* __restrict__ dst, int E, int chunk,
                       int* __restrict__ hist) {
    __shared__ int bin[NP];
    if (threadIdx.x < NP) bin[threadIdx.x] = 0;
    __syncthreads();
    int beg = blockIdx.x * chunk;
    int end = beg + chunk; if (end > E) end = E;
    for (int e = beg + threadIdx.x; e < end; e += 256)
        atomicAdd(&bin[dst[e] >> BSH], 1);
    __syncthreads();
    if (threadIdx.x < NP)
        hist[blockIdx.x * NP + threadIdx.x] = bin[threadIdx.x];
}

// bucket totals + exclusive scan -> base[0..NP], base[NP]=E   (1 block x NP)
__global__ void k_s1(const int* __restrict__ hist, int* __restrict__ base) {
    __shared__ int sh[NP];
    int b = threadIdx.x;
    int s = 0;
    #pragma unroll 8
    for (int k = 0; k < NB; ++k) s += hist[k * NP + b];
    sh[b] = s;
    __syncthreads();
    for (int off = 1; off < NP; off <<= 1) {
        int u = (b >= off) ? sh[b - off] : 0;
        __syncthreads();
        sh[b] += u;
        __syncthreads();
    }
    base[b] = sh[b] - s;
    if (b == NP - 1) base[NP] = sh[b];
}

// per-bucket scan over block counts: hist[k][b] := base[b] + sum_{k'<k} hist[k'][b]
__global__ void k_s2(int* __restrict__ hist, const int* __restrict__ base) {
    __shared__ int sh[NB];
    int b = blockIdx.x, t = threadIdx.x;
    int v = hist[t * NP + b];
    sh[t] = v;
    __syncthreads();
    for (int off = 1; off < NB; off <<= 1) {
        int u = (t >= off) ? sh[t - off] : 0;
        __syncthreads();
        sh[t] += u;
        __syncthreads();
    }
    hist[t * NP + b] = base[b] + sh[t] - v;
}

// partition edges into bucket-grouped part[]: value = (src<<BSH) | (dst&BMASK)
__global__ void k_part(const int* __restrict__ src, const int* __restrict__ dst,
                       int E, int chunk, const int* __restrict__ hist,
                       unsigned int* __restrict__ part) {
    __shared__ int cur[NP];
    if (threadIdx.x < NP)
        cur[threadIdx.x] = hist[blockIdx.x * NP + threadIdx.x];
    __syncthreads();
    int beg = blockIdx.x * chunk;
    int end = beg + chunk; if (end > E) end = E;
    for (int e = beg + threadIdx.x; e < end; e += 256) {
        int d = dst[e];
        int p = atomicAdd(&cur[d >> BSH], 1);
        part[p] = ((unsigned)src[e] << BSH) | ((unsigned)d & BMASK);
    }
}

// per-bucket (512 threads): deg -> offs; prescaled xp4 (w = dinv); local scatter -> col
__global__ void k_csr(const unsigned int* __restrict__ part, const int* __restrict__ base,
                      const float* __restrict__ x,
                      int* __restrict__ offs,
                      float4* __restrict__ xp4, int* __restrict__ col, int N) {
    __shared__ int cnt[512];
    __shared__ int scn[512];
    __shared__ int cur[512];
    int b = blockIdx.x, t = threadIdx.x;
    int lo = base[b], hi = base[b + 1];
    cnt[t] = 0;
    __syncthreads();
    for (int e = lo + t; e < hi; e += 512)
        atomicAdd(&cnt[part[e] & BMASK], 1);
    __syncthreads();
    int v = cnt[t];
    scn[t] = v;
    __syncthreads();
    for (int off = 1; off < 512; off <<= 1) {
        int u = (t >= off) ? scn[t - off] : 0;
        __syncthreads();
        scn[t] += u;
        __syncthreads();
    }
    {
        int pos = lo + scn[t] - v;        // exclusive
        cur[t] = pos;
        int g = (b << BSH) + t;
        if (g < N) {
            offs[g] = pos;
            float di = rsqrtf((float)(v + 1));   // +1 self-loop
            xp4[g] = make_float4(x[3*g] * di, x[3*g+1] * di, x[3*g+2] * di, di);
        }
    }
    if (b == 0 && t == 0) offs[N] = base[(N_NODES + 511) >> BSH];
    __syncthreads();
    for (int e = lo + t; e < hi; e += 512) {
        unsigned int w = part[e];
        int p = atomicAdd(&cur[w & BMASK], 1);
        col[p] = (int)(w >> BSH);
    }
}

// ================= fallback CSR build (global atomics) ==========

__global__ void k_deg(const int* __restrict__ dst, int E, int* __restrict__ deg) {
    int e = blockIdx.x * blockDim.x + threadIdx.x;
    if (e < E) atomicAdd(&deg[dst[e]], 1);
}

__global__ void k_scan1(const int* __restrict__ deg, int* __restrict__ offs,
                        int* __restrict__ partl, int N) {
    __shared__ int sh[256];
    int i = blockIdx.x * 256 + threadIdx.x;
    int t = threadIdx.x;
    int v = (i < N) ? deg[i] : 0;
    sh[t] = v;
    __syncthreads();
    #pragma unroll
    for (int off = 1; off < 256; off <<= 1) {
        int u = (t >= off) ? sh[t - off] : 0;
        __syncthreads();
        sh[t] += u;
        __syncthreads();
    }
    if (i < N) offs[i] = sh[t] - v;
    if (t == 255) partl[blockIdx.x] = sh[255];
}

__global__ void k_scan2(int* __restrict__ partl, int* __restrict__ offs, int nb, int N) {
    __shared__ int sh[1024];
    int t = threadIdx.x;
    int v = (t < nb) ? partl[t] : 0;
    sh[t] = v;
    __syncthreads();
    #pragma unroll
    for (int off = 1; off < 1024; off <<= 1) {
        int u = (t >= off) ? sh[t - off] : 0;
        __syncthreads();
        sh[t] += u;
        __syncthreads();
    }
    if (t < nb) partl[t] = sh[t] - v;
    if (t == 1023) offs[N] = sh[1023];
}

__global__ void k_scan3(int* __restrict__ offs, const int* __restrict__ partl, int N) {
    int i = blockIdx.x * 256 + threadIdx.x;
    if (i < N) offs[i] += partl[blockIdx.x];
}

__global__ void k_fill_cur(const int* __restrict__ src, const int* __restrict__ dst,
                           const int* __restrict__ offs, int* __restrict__ cur,
                           int* __restrict__ col, int E) {
    int e = blockIdx.x * blockDim.x + threadIdx.x;
    if (e >= E) return;
    int d = dst[e];
    col[offs[d] + atomicAdd(&cur[d], 1)] = src[e];
}

__global__ void k_prescale(const float* __restrict__ x, const int* __restrict__ offs,
                           float4* __restrict__ xp4, int N) {
    int i = blockIdx.x * blockDim.x + threadIdx.x;
    if (i >= N) return;
    int d = offs[i+1] - offs[i];
    float di = rsqrtf((float)(d + 1));
    xp4[i] = make_float4(x[3*i] * di, x[3*i+1] * di, x[3*i+2] * di, di);
}

// ================= convs: G lanes per node, float4 gathers =================

__global__ void k_conv1(const int* __restrict__ offs, const int* __restrict__ col,
                        const float4* __restrict__ xp4,
                        const float* __restrict__ W1, const float* __restrict__ b1,
                        const float* __restrict__ W2,
                        float4* __restrict__ h2p4, int N) {
    int tid = blockIdx.x * blockDim.x + threadIdx.x;
    int i = tid >> 3, g = tid & (G - 1);
    if (i >= N) return;
    float s0 = 0.f, s1 = 0.f, s2 = 0.f, di = 0.f;
    if (g == 0) {
        float4 self = xp4[i];          // self-loop term (already * di)
        s0 = self.x; s1 = self.y; s2 = self.z; di = self.w;
    }
    int beg = offs[i], end = offs[i+1];
    for (int k = beg + g; k < end; k += G) {
        float4 v = xp4[col[k]];
        s0 += v.x; s1 += v.y; s2 += v.z;
    }
    #pragma unroll
    for (int off = G/2; off > 0; off >>= 1) {
        s0 += __shfl_down(s0, off, G);
        s1 += __shfl_down(s1, off, G);
        s2 += __shfl_down(s2, off, G);
    }
    if (g == 0) {
        float g0 = s0 * di, g1 = s1 * di, g2 = s2 * di;   // (Âx)[i]
        float o0 = 0.f, o1 = 0.f, o2 = 0.f;
        #pragma unroll
        for (int j = 0; j < 16; ++j) {
            float t = fmaxf(g0 * W1[j] + g1 * W1[16 + j] + g2 * W1[32 + j] + b1[j], 0.f);
            o0 += t * W2[3*j + 0];
            o1 += t * W2[3*j + 1];
            o2 += t * W2[3*j + 2];
        }
        h2p4[i] = make_float4(o0 * di, o1 * di, o2 * di, di);
    }
}

__global__ void k_conv2(const int* __restrict__ offs, const int* __restrict__ col,
                        const float4* __restrict__ h2p4,
                        const float* __restrict__ b2, const float* __restrict__ W3,
                        float* __restrict__ embed_out, float4* __restrict__ h3p4, int N) {
    int tid = blockIdx.x * blockDim.x + threadIdx.x;
    int i = tid >> 3, g = tid & (G - 1);
    if (i >= N) return;
    float s0 = 0.f, s1 = 0.f, s2 = 0.f, di = 0.f;
    if (g == 0) {
        float4 self = h2p4[i];
        s0 = self.x; s1 = self.y; s2 = self.z; di = self.w;
    }
    int beg = offs[i], end = offs[i+1];
    for (int k = beg + g; k < end; k += G) {
        float4 v = h2p4[col[k]];
        s0 += v.x; s1 += v.y; s2 += v.z;
    }
    #pragma unroll
    for (int off = G/2; off > 0; off >>= 1) {
        s0 += __shfl_down(s0, off, G);
        s1 += __shfl_down(s1, off, G);
        s2 += __shfl_down(s2, off, G);
    }
    if (g == 0) {
        float t0 = s0 * di + b2[0];
        float t1 = s1 * di + b2[1];
        float t2 = s2 * di + b2[2];
        float inv = 1.0f / fmaxf(sqrtf(t0*t0 + t1*t1 + t2*t2), 1e-12f);
        float e0 = t0*inv, e1 = t1*inv, e2 = t2*inv;
        embed_out[3*i] = e0; embed_out[3*i+1] = e1; embed_out[3*i+2] = e2;
        h3p4[i] = make_float4((e0*W3[0] + e1*W3[3] + e2*W3[6]) * di,
                              (e0*W3[1] + e1*W3[4] + e2*W3[7]) * di,
                              (e0*W3[2] + e1*W3[5] + e2*W3[8]) * di, di);
    }
}

// conv3: no global atomics — block partial sums to pool[blockIdx]
__global__ void k_conv3(const int* __restrict__ offs, const int* __restrict__ col,
                        const float4* __restrict__ h3p4,
                        const float* __restrict__ b3, const float* __restrict__ Wp,
                        const float* __restrict__ bp,
                        float* __restrict__ hout, float* __restrict__ pool, int N) {
    __shared__ float psum[3];
    if (threadIdx.x == 0) { psum[0] = 0.f; psum[1] = 0.f; psum[2] = 0.f; }
    __syncthreads();
    int tid = blockIdx.x * blockDim.x + threadIdx.x;
    int i = tid >> 3, g = tid & (G - 1);
    float p0 = 0.f, p1 = 0.f, p2 = 0.f;
    if (i < N) {
        float s0 = 0.f, s1 = 0.f, s2 = 0.f, di = 0.f;
        if (g == 0) {
            float4 self = h3p4[i];
            s0 = self.x; s1 = self.y; s2 = self.z; di = self.w;
        }
        int beg = offs[i], end = offs[i+1];
        for (int k = beg + g; k < end; k += G) {
            float4 v = h3p4[col[k]];
            s0 += v.x; s1 += v.y; s2 += v.z;
        }
        #pragma unroll
        for (int off = G/2; off > 0; off >>= 1) {
            s0 += __shfl_down(s0, off, G);
            s1 += __shfl_down(s1, off, G);
            s2 += __shfl_down(s2, off, G);
        }
        if (g == 0) {
            float t0 = s0 * di + b3[0];
            float t1 = s1 * di + b3[1];
            float t2 = s2 * di + b3[2];
            p0 = t0*Wp[0] + t1*Wp[3] + t2*Wp[6] + bp[0];
            p1 = t0*Wp[1] + t1*Wp[4] + t2*Wp[7] + bp[1];
            p2 = t0*Wp[2] + t1*Wp[5] + t2*Wp[8] + bp[2];
            hout[3*i] = p0; hout[3*i+1] = p1; hout[3*i+2] = p2;
        }
    }
    #pragma unroll
    for (int off = 32; off > 0; off >>= 1) {
        p0 += __shfl_down(p0, off);
        p1 += __shfl_down(p1, off);
        p2 += __shfl_down(p2, off);
    }
    if ((threadIdx.x & 63) == 0) {
        atomicAdd(&psum[0], p0);
        atomicAdd(&psum[1], p1);
        atomicAdd(&psum[2], p2);
    }
    __syncthreads();
    if (threadIdx.x == 0) {
        pool[3*blockIdx.x]   = psum[0];
        pool[3*blockIdx.x+1] = psum[1];
        pool[3*blockIdx.x+2] = psum[2];
    }
}

// head: deterministic reduce of block partials, then logits + log_softmax
__global__ void k_head(const float* __restrict__ pool, int nb,
                       const float* __restrict__ Wl, const float* __restrict__ bl,
                       float* __restrict__ out, int N) {
    __shared__ float sh[12];  // 4 waves x 3
    int t = threadIdx.x;
    float p0 = 0.f, p1 = 0.f, p2 = 0.f;
    for (int k = t; k < nb; k += 256) {
        p0 += pool[3*k]; p1 += pool[3*k+1]; p2 += pool[3*k+2];
    }
    #pragma unroll
    for (int off = 32; off > 0; off >>= 1) {
        p0 += __shfl_down(p0, off);
        p1 += __shfl_down(p1, off);
        p2 += __shfl_down(p2, off);
    }
    if ((t & 63) == 0) {
        int w = t >> 6;
        sh[3*w] = p0; sh[3*w+1] = p1; sh[3*w+2] = p2;
    }
    __syncthreads();
    if (t == 0) {
        p0 = sh[0] + sh[3] + sh[6] + sh[9];
        p1 = sh[1] + sh[4] + sh[7] + sh[10];
        p2 = sh[2] + sh[5] + sh[8] + sh[11];
        p0 /= (float)N; p1 /= (float)N; p2 /= (float)N;
        float l[10];
        float m = -1e30f;
        #pragma unroll
        for (int j = 0; j < 10; ++j) {
            l[j] = p0 * Wl[j] + p1 * Wl[10 + j] + p2 * Wl[20 + j] + bl[j];
            m = fmaxf(m, l[j]);
        }
        float s = 0.f;
        #pragma unroll
        for (int j = 0; j < 10; ++j) s += expf(l[j] - m);
        float lse = logf(s) + m;
        #pragma unroll
        for (int j = 0; j < 10; ++j) out[j] = l[j] - lse;
    }
}

extern "C" void kernel_launch(void* const* d_in, const int* in_sizes, int n_in,
                              void* d_out, int out_size, void* d_ws, size_t ws_size,
                              hipStream_t stream) {
    const int N = N_NODES;
    const float* x  = (const float*)d_in[0];
    const int*   ei = (const int*)d_in[1];
    const int    E  = in_sizes[1] / 2;
    const int* src = ei;
    const int* dst = ei + E;
    const float* W1 = (const float*)d_in[2];
    const float* b1 = (const float*)d_in[3];
    const float* W2 = (const float*)d_in[4];
    const float* b2 = (const float*)d_in[5];
    const float* W3 = (const float*)d_in[6];
    const float* b3 = (const float*)d_in[7];
    const float* Wp = (const float*)d_in[8];
    const float* bp = (const float*)d_in[9];
    const float* Wl = (const float*)d_in[10];
    const float* bl = (const float*)d_in[11];

    float* out     = (float*)d_out;
    float* h_out   = out + 10;              // [N,3]
    float* emb_out = out + 10 + 3 * N;      // [N,3]

    const int B = 256;
    int gE = (E + B - 1) / B;
    int gN = (N + B - 1) / B;
    int gC = ((size_t)N * G + B - 1) / B;   // conv grid (3125 blocks)
    int chunk = (E + NB - 1) / NB;
    int PB = (N + 511) >> BSH;              // 196 buckets

    char* Wm = (char*)d_ws;

    // ---- bucket-path layout ----
    size_t off = 0;
    auto alloc = [&](size_t elems) { void* p = Wm + off; off += elems * 4; return p; };
    int*          col  = (int*)alloc((size_t)E);
    unsigned int* part = (unsigned int*)alloc((size_t)E);
    int*          hist = (int*)alloc((size_t)NB * NP);
    int*          base = (int*)alloc(NP + 1);
    int*          offs = (int*)alloc(N + 1);
    float4*       bufA = (float4*)alloc(4 * N);
    float4*       bufB = (float4*)alloc(4 * N);
    float*        pool = (float*)alloc(3 * (size_t)gC + 4);
    size_t need_bucket = off;

    if (ws_size >= need_bucket) {
        k_hist<<<NB, B, 0, stream>>>(dst, E, chunk, hist);
        k_s1<<<1, NP, 0, stream>>>(hist, base);
        k_s2<<<NP, NB, 0, stream>>>(hist, base);
        k_part<<<NB, B, 0, stream>>>(src, dst, E, chunk, hist, part);
        k_csr<<<PB, 512, 0, stream>>>(part, base, x, offs, bufA, col, N);
    } else {
        // ---- fallback layout ----
        off = 0;
        col  = (int*)alloc((size_t)E);
        int* deg = (int*)alloc(N);
        offs = (int*)alloc(N + 1);
        bufA = (float4*)alloc(4 * N);
        bufB = (float4*)alloc(4 * N);
        pool = (float*)alloc(3 * (size_t)gC + 4);
        int* partl = (int*)alloc(1024);
        int* cur = (int*)alloc(N);

        hipMemsetAsync(deg, 0, N * sizeof(int), stream);
        hipMemsetAsync(cur, 0, N * sizeof(int), stream);

        k_deg<<<gE, B, 0, stream>>>(dst, E, deg);
        k_scan1<<<gN, B, 0, stream>>>(deg, offs, partl, N);
        k_scan2<<<1, 1024, 0, stream>>>(partl, offs, gN, N);
        k_scan3<<<gN, B, 0, stream>>>(offs, partl, N);
        k_fill_cur<<<gE, B, 0, stream>>>(src, dst, offs, cur, col, E);
        k_prescale<<<gN, B, 0, stream>>>(x, offs, bufA, N);
    }

    // convs: G lanes/node, float4 gathers, dinv carried in .w
    k_conv1<<<gC, B, 0, stream>>>(offs, col, bufA, W1, b1, W2, bufB, N);
    k_conv2<<<gC, B, 0, stream>>>(offs, col, bufB, b2, W3, emb_out, bufA, N);
    k_conv3<<<gC, B, 0, stream>>>(offs, col, bufA, b3, Wp, bp, h_out, pool, N);

    k_head<<<1, 256, 0, stream>>>(pool, gC, Wl, bl, out, N);
}

// Round 8
// 140.667 us; speedup vs baseline: 4.5474x; 1.1972x over previous
//
#include <hip/hip_runtime.h>
#include <math.h>

#define N_NODES 100000
#define NB 256          // partition blocks
#define NP 256          // buckets (dst >> 9), 512 nodes per bucket
#define BSH 9           // bucket shift
#define BMASK 511u      // node-in-bucket mask
#define G 8             // lanes per node in conv gathers

// ================= bucket-path CSR build (no global atomics) =================
// k_hist / k_part: 1024 threads, int4 edge reads, block b handles groups
// [b*gchunk, (b+1)*gchunk) of 4 edges; block 0 also takes the scalar tail.

__global__ void k_hist(const int* __restrict__ dst, int E,
                       int* __restrict__ hist) {
    __shared__ int bin[NP];
    if (threadIdx.x < NP) bin[threadIdx.x] = 0;
    __syncthreads();
    int ngroups = E >> 2;
    int gchunk = (ngroups + NB - 1) / NB;
    int gbeg = blockIdx.x * gchunk;
    int gend = gbeg + gchunk; if (gend > ngroups) gend = ngroups;
    const int4* d4 = (const int4*)dst;
    for (int g = gbeg + threadIdx.x; g < gend; g += 1024) {
        int4 d = d4[g];
        atomicAdd(&bin[d.x >> BSH], 1);
        atomicAdd(&bin[d.y >> BSH], 1);
        atomicAdd(&bin[d.z >> BSH], 1);
        atomicAdd(&bin[d.w >> BSH], 1);
    }
    if (blockIdx.x == 0) {
        for (int e = (ngroups << 2) + threadIdx.x; e < E; e += 1024)
            atomicAdd(&bin[dst[e] >> BSH], 1);
    }
    __syncthreads();
    if (threadIdx.x < NP)
        hist[blockIdx.x * NP + threadIdx.x] = bin[threadIdx.x];
}

// bucket totals + exclusive scan -> base[0..NP], base[NP]=E   (1 block x NP)
__global__ void k_s1(const int* __restrict__ hist, int* __restrict__ base) {
    __shared__ int sh[NP];
    int b = threadIdx.x;
    int s = 0;
    #pragma unroll 8
    for (int k = 0; k < NB; ++k) s += hist[k * NP + b];
    sh[b] = s;
    __syncthreads();
    for (int off = 1; off < NP; off <<= 1) {
        int u = (b >= off) ? sh[b - off] : 0;
        __syncthreads();
        sh[b] += u;
        __syncthreads();
    }
    base[b] = sh[b] - s;
    if (b == NP - 1) base[NP] = sh[b];
}

// per-bucket scan over block counts: hist[k][b] := base[b] + sum_{k'<k} hist[k'][b]
__global__ void k_s2(int* __restrict__ hist, const int* __restrict__ base) {
    __shared__ int sh[NB];
    int b = blockIdx.x, t = threadIdx.x;
    int v = hist[t * NP + b];
    sh[t] = v;
    __syncthreads();
    for (int off = 1; off < NB; off <<= 1) {
        int u = (t >= off) ? sh[t - off] : 0;
        __syncthreads();
        sh[t] += u;
        __syncthreads();
    }
    hist[t * NP + b] = base[b] + sh[t] - v;
}

// partition edges into bucket-grouped part[]: value = (src<<BSH) | (dst&BMASK)
__global__ void k_part(const int* __restrict__ src, const int* __restrict__ dst,
                       int E, const int* __restrict__ hist,
                       unsigned int* __restrict__ part) {
    __shared__ int cur[NP];
    if (threadIdx.x < NP)
        cur[threadIdx.x] = hist[blockIdx.x * NP + threadIdx.x];
    __syncthreads();
    int ngroups = E >> 2;
    int gchunk = (ngroups + NB - 1) / NB;
    int gbeg = blockIdx.x * gchunk;
    int gend = gbeg + gchunk; if (gend > ngroups) gend = ngroups;
    const int4* d4 = (const int4*)dst;
    const int4* s4 = (const int4*)src;
    for (int g = gbeg + threadIdx.x; g < gend; g += 1024) {
        int4 d = d4[g];
        int4 s = s4[g];
        int p;
        p = atomicAdd(&cur[d.x >> BSH], 1);
        part[p] = ((unsigned)s.x << BSH) | ((unsigned)d.x & BMASK);
        p = atomicAdd(&cur[d.y >> BSH], 1);
        part[p] = ((unsigned)s.y << BSH) | ((unsigned)d.y & BMASK);
        p = atomicAdd(&cur[d.z >> BSH], 1);
        part[p] = ((unsigned)s.z << BSH) | ((unsigned)d.z & BMASK);
        p = atomicAdd(&cur[d.w >> BSH], 1);
        part[p] = ((unsigned)s.w << BSH) | ((unsigned)d.w & BMASK);
    }
    if (blockIdx.x == 0) {
        for (int e = (ngroups << 2) + threadIdx.x; e < E; e += 1024) {
            int d = dst[e];
            int p = atomicAdd(&cur[d >> BSH], 1);
            part[p] = ((unsigned)src[e] << BSH) | ((unsigned)d & BMASK);
        }
    }
}

// per-bucket (1024 threads): deg -> offs; prescaled xp4 (w = dinv); local scatter -> col
__global__ void k_csr(const unsigned int* __restrict__ part, const int* __restrict__ base,
                      const float* __restrict__ x,
                      int* __restrict__ offs,
                      float4* __restrict__ xp4, int* __restrict__ col, int N) {
    __shared__ int cnt[512];
    __shared__ int scn[512];
    __shared__ int cur[512];
    int b = blockIdx.x, t = threadIdx.x;
    int lo = base[b], hi = base[b + 1];
    if (t < 512) cnt[t] = 0;
    __syncthreads();
    for (int e = lo + t; e < hi; e += 1024)
        atomicAdd(&cnt[part[e] & BMASK], 1);
    __syncthreads();
    int v = (t < 512) ? cnt[t] : 0;
    if (t < 512) scn[t] = v;
    __syncthreads();
    for (int off = 1; off < 512; off <<= 1) {
        int u = (t < 512 && t >= off) ? scn[t - off] : 0;
        __syncthreads();
        if (t < 512) scn[t] += u;
        __syncthreads();
    }
    if (t < 512) {
        int pos = lo + scn[t] - v;        // exclusive
        cur[t] = pos;
        int g = (b << BSH) + t;
        if (g < N) {
            offs[g] = pos;
            float di = rsqrtf((float)(v + 1));   // +1 self-loop
            xp4[g] = make_float4(x[3*g] * di, x[3*g+1] * di, x[3*g+2] * di, di);
        }
    }
    if (b == 0 && t == 0) offs[N] = base[(N_NODES + 511) >> BSH];
    __syncthreads();
    for (int e = lo + t; e < hi; e += 1024) {
        unsigned int w = part[e];
        int p = atomicAdd(&cur[w & BMASK], 1);
        col[p] = (int)(w >> BSH);
    }
}

// ================= fallback CSR build (global atomics) ==========

__global__ void k_deg(const int* __restrict__ dst, int E, int* __restrict__ deg) {
    int e = blockIdx.x * blockDim.x + threadIdx.x;
    if (e < E) atomicAdd(&deg[dst[e]], 1);
}

__global__ void k_scan1(const int* __restrict__ deg, int* __restrict__ offs,
                        int* __restrict__ partl, int N) {
    __shared__ int sh[256];
    int i = blockIdx.x * 256 + threadIdx.x;
    int t = threadIdx.x;
    int v = (i < N) ? deg[i] : 0;
    sh[t] = v;
    __syncthreads();
    #pragma unroll
    for (int off = 1; off < 256; off <<= 1) {
        int u = (t >= off) ? sh[t - off] : 0;
        __syncthreads();
        sh[t] += u;
        __syncthreads();
    }
    if (i < N) offs[i] = sh[t] - v;
    if (t == 255) partl[blockIdx.x] = sh[255];
}

__global__ void k_scan2(int* __restrict__ partl, int* __restrict__ offs, int nb, int N) {
    __shared__ int sh[1024];
    int t = threadIdx.x;
    int v = (t < nb) ? partl[t] : 0;
    sh[t] = v;
    __syncthreads();
    #pragma unroll
    for (int off = 1; off < 1024; off <<= 1) {
        int u = (t >= off) ? sh[t - off] : 0;
        __syncthreads();
        sh[t] += u;
        __syncthreads();
    }
    if (t < nb) partl[t] = sh[t] - v;
    if (t == 1023) offs[N] = sh[1023];
}

__global__ void k_scan3(int* __restrict__ offs, const int* __restrict__ partl, int N) {
    int i = blockIdx.x * 256 + threadIdx.x;
    if (i < N) offs[i] += partl[blockIdx.x];
}

__global__ void k_fill_cur(const int* __restrict__ src, const int* __restrict__ dst,
                           const int* __restrict__ offs, int* __restrict__ cur,
                           int* __restrict__ col, int E) {
    int e = blockIdx.x * blockDim.x + threadIdx.x;
    if (e >= E) return;
    int d = dst[e];
    col[offs[d] + atomicAdd(&cur[d], 1)] = src[e];
}

__global__ void k_prescale(const float* __restrict__ x, const int* __restrict__ offs,
                           float4* __restrict__ xp4, int N) {
    int i = blockIdx.x * blockDim.x + threadIdx.x;
    if (i >= N) return;
    int d = offs[i+1] - offs[i];
    float di = rsqrtf((float)(d + 1));
    xp4[i] = make_float4(x[3*i] * di, x[3*i+1] * di, x[3*i+2] * di, di);
}

// ================= convs: G lanes per node, float4 gathers =================

__global__ void k_conv1(const int* __restrict__ offs, const int* __restrict__ col,
                        const float4* __restrict__ xp4,
                        const float* __restrict__ W1, const float* __restrict__ b1,
                        const float* __restrict__ W2,
                        float4* __restrict__ h2p4, int N) {
    int tid = blockIdx.x * blockDim.x + threadIdx.x;
    int i = tid >> 3, g = tid & (G - 1);
    if (i >= N) return;
    float s0 = 0.f, s1 = 0.f, s2 = 0.f, di = 0.f;
    if (g == 0) {
        float4 self = xp4[i];          // self-loop term (already * di)
        s0 = self.x; s1 = self.y; s2 = self.z; di = self.w;
    }
    int beg = offs[i], end = offs[i+1];
    for (int k = beg + g; k < end; k += G) {
        float4 v = xp4[col[k]];
        s0 += v.x; s1 += v.y; s2 += v.z;
    }
    #pragma unroll
    for (int off = G/2; off > 0; off >>= 1) {
        s0 += __shfl_down(s0, off, G);
        s1 += __shfl_down(s1, off, G);
        s2 += __shfl_down(s2, off, G);
    }
    if (g == 0) {
        float g0 = s0 * di, g1 = s1 * di, g2 = s2 * di;   // (Âx)[i]
        float o0 = 0.f, o1 = 0.f, o2 = 0.f;
        #pragma unroll
        for (int j = 0; j < 16; ++j) {
            float t = fmaxf(g0 * W1[j] + g1 * W1[16 + j] + g2 * W1[32 + j] + b1[j], 0.f);
            o0 += t * W2[3*j + 0];
            o1 += t * W2[3*j + 1];
            o2 += t * W2[3*j + 2];
        }
        h2p4[i] = make_float4(o0 * di, o1 * di, o2 * di, di);
    }
}

__global__ void k_conv2(const int* __restrict__ offs, const int* __restrict__ col,
                        const float4* __restrict__ h2p4,
                        const float* __restrict__ b2, const float* __restrict__ W3,
                        float* __restrict__ embed_out, float4* __restrict__ h3p4, int N) {
    int tid = blockIdx.x * blockDim.x + threadIdx.x;
    int i = tid >> 3, g = tid & (G - 1);
    if (i >= N) return;
    float s0 = 0.f, s1 = 0.f, s2 = 0.f, di = 0.f;
    if (g == 0) {
        float4 self = h2p4[i];
        s0 = self.x; s1 = self.y; s2 = self.z; di = self.w;
    }
    int beg = offs[i], end = offs[i+1];
    for (int k = beg + g; k < end; k += G) {
        float4 v = h2p4[col[k]];
        s0 += v.x; s1 += v.y; s2 += v.z;
    }
    #pragma unroll
    for (int off = G/2; off > 0; off >>= 1) {
        s0 += __shfl_down(s0, off, G);
        s1 += __shfl_down(s1, off, G);
        s2 += __shfl_down(s2, off, G);
    }
    if (g == 0) {
        float t0 = s0 * di + b2[0];
        float t1 = s1 * di + b2[1];
        float t2 = s2 * di + b2[2];
        float inv = 1.0f / fmaxf(sqrtf(t0*t0 + t1*t1 + t2*t2), 1e-12f);
        float e0 = t0*inv, e1 = t1*inv, e2 = t2*inv;
        embed_out[3*i] = e0; embed_out[3*i+1] = e1; embed_out[3*i+2] = e2;
        h3p4[i] = make_float4((e0*W3[0] + e1*W3[3] + e2*W3[6]) * di,
                              (e0*W3[1] + e1*W3[4] + e2*W3[7]) * di,
                              (e0*W3[2] + e1*W3[5] + e2*W3[8]) * di, di);
    }
}

// conv3: no global atomics — block partial sums to pool[blockIdx]
__global__ void k_conv3(const int* __restrict__ offs, const int* __restrict__ col,
                        const float4* __restrict__ h3p4,
                        const float* __restrict__ b3, const float* __restrict__ Wp,
                        const float* __restrict__ bp,
                        float* __restrict__ hout, float* __restrict__ pool, int N) {
    __shared__ float psum[3];
    if (threadIdx.x == 0) { psum[0] = 0.f; psum[1] = 0.f; psum[2] = 0.f; }
    __syncthreads();
    int tid = blockIdx.x * blockDim.x + threadIdx.x;
    int i = tid >> 3, g = tid & (G - 1);
    float p0 = 0.f, p1 = 0.f, p2 = 0.f;
    if (i < N) {
        float s0 = 0.f, s1 = 0.f, s2 = 0.f, di = 0.f;
        if (g == 0) {
            float4 self = h3p4[i];
            s0 = self.x; s1 = self.y; s2 = self.z; di = self.w;
        }
        int beg = offs[i], end = offs[i+1];
        for (int k = beg + g; k < end; k += G) {
            float4 v = h3p4[col[k]];
            s0 += v.x; s1 += v.y; s2 += v.z;
        }
        #pragma unroll
        for (int off = G/2; off > 0; off >>= 1) {
            s0 += __shfl_down(s0, off, G);
            s1 += __shfl_down(s1, off, G);
            s2 += __shfl_down(s2, off, G);
        }
        if (g == 0) {
            float t0 = s0 * di + b3[0];
            float t1 = s1 * di + b3[1];
            float t2 = s2 * di + b3[2];
            p0 = t0*Wp[0] + t1*Wp[3] + t2*Wp[6] + bp[0];
            p1 = t0*Wp[1] + t1*Wp[4] + t2*Wp[7] + bp[1];
            p2 = t0*Wp[2] + t1*Wp[5] + t2*Wp[8] + bp[2];
            hout[3*i] = p0; hout[3*i+1] = p1; hout[3*i+2] = p2;
        }
    }
    #pragma unroll
    for (int off = 32; off > 0; off >>= 1) {
        p0 += __shfl_down(p0, off);
        p1 += __shfl_down(p1, off);
        p2 += __shfl_down(p2, off);
    }
    if ((threadIdx.x & 63) == 0) {
        atomicAdd(&psum[0], p0);
        atomicAdd(&psum[1], p1);
        atomicAdd(&psum[2], p2);
    }
    __syncthreads();
    if (threadIdx.x == 0) {
        pool[3*blockIdx.x]   = psum[0];
        pool[3*blockIdx.x+1] = psum[1];
        pool[3*blockIdx.x+2] = psum[2];
    }
}

// head: deterministic reduce of block partials, then logits + log_softmax
__global__ void k_head(const float* __restrict__ pool, int nb,
                       const float* __restrict__ Wl, const float* __restrict__ bl,
                       float* __restrict__ out, int N) {
    __shared__ float sh[12];  // 4 waves x 3
    int t = threadIdx.x;
    float p0 = 0.f, p1 = 0.f, p2 = 0.f;
    for (int k = t; k < nb; k += 256) {
        p0 += pool[3*k]; p1 += pool[3*k+1]; p2 += pool[3*k+2];
    }
    #pragma unroll
    for (int off = 32; off > 0; off >>= 1) {
        p0 += __shfl_down(p0, off);
        p1 += __shfl_down(p1, off);
        p2 += __shfl_down(p2, off);
    }
    if ((t & 63) == 0) {
        int w = t >> 6;
        sh[3*w] = p0; sh[3*w+1] = p1; sh[3*w+2] = p2;
    }
    __syncthreads();
    if (t == 0) {
        p0 = sh[0] + sh[3] + sh[6] + sh[9];
        p1 = sh[1] + sh[4] + sh[7] + sh[10];
        p2 = sh[2] + sh[5] + sh[8] + sh[11];
        p0 /= (float)N; p1 /= (float)N; p2 /= (float)N;
        float l[10];
        float m = -1e30f;
        #pragma unroll
        for (int j = 0; j < 10; ++j) {
            l[j] = p0 * Wl[j] + p1 * Wl[10 + j] + p2 * Wl[20 + j] + bl[j];
            m = fmaxf(m, l[j]);
        }
        float s = 0.f;
        #pragma unroll
        for (int j = 0; j < 10; ++j) s += expf(l[j] - m);
        float lse = logf(s) + m;
        #pragma unroll
        for (int j = 0; j < 10; ++j) out[j] = l[j] - lse;
    }
}

extern "C" void kernel_launch(void* const* d_in, const int* in_sizes, int n_in,
                              void* d_out, int out_size, void* d_ws, size_t ws_size,
                              hipStream_t stream) {
    const int N = N_NODES;
    const float* x  = (const float*)d_in[0];
    const int*   ei = (const int*)d_in[1];
    const int    E  = in_sizes[1] / 2;
    const int* src = ei;
    const int* dst = ei + E;
    const float* W1 = (const float*)d_in[2];
    const float* b1 = (const float*)d_in[3];
    const float* W2 = (const float*)d_in[4];
    const float* b2 = (const float*)d_in[5];
    const float* W3 = (const float*)d_in[6];
    const float* b3 = (const float*)d_in[7];
    const float* Wp = (const float*)d_in[8];
    const float* bp = (const float*)d_in[9];
    const float* Wl = (const float*)d_in[10];
    const float* bl = (const float*)d_in[11];

    float* out     = (float*)d_out;
    float* h_out   = out + 10;              // [N,3]
    float* emb_out = out + 10 + 3 * N;      // [N,3]

    const int B = 256;
    int gE = (E + B - 1) / B;
    int gN = (N + B - 1) / B;
    int gC = ((size_t)N * G + B - 1) / B;   // conv grid (3125 blocks)
    int PB = (N + 511) >> BSH;              // 196 buckets

    char* Wm = (char*)d_ws;

    // ---- bucket-path layout ----
    size_t off = 0;
    auto alloc = [&](size_t elems) { void* p = Wm + off; off += elems * 4; return p; };
    int*          col  = (int*)alloc((size_t)E);
    unsigned int* part = (unsigned int*)alloc((size_t)E);
    int*          hist = (int*)alloc((size_t)NB * NP);
    int*          base = (int*)alloc(NP + 1);
    int*          offs = (int*)alloc(N + 1);
    float4*       bufA = (float4*)alloc(4 * N);
    float4*       bufB = (float4*)alloc(4 * N);
    float*        pool = (float*)alloc(3 * (size_t)gC + 4);
    size_t need_bucket = off;

    if (ws_size >= need_bucket) {
        k_hist<<<NB, 1024, 0, stream>>>(dst, E, hist);
        k_s1<<<1, NP, 0, stream>>>(hist, base);
        k_s2<<<NP, NB, 0, stream>>>(hist, base);
        k_part<<<NB, 1024, 0, stream>>>(src, dst, E, hist, part);
        k_csr<<<PB, 1024, 0, stream>>>(part, base, x, offs, bufA, col, N);
    } else {
        // ---- fallback layout ----
        off = 0;
        col  = (int*)alloc((size_t)E);
        int* deg = (int*)alloc(N);
        offs = (int*)alloc(N + 1);
        bufA = (float4*)alloc(4 * N);
        bufB = (float4*)alloc(4 * N);
        pool = (float*)alloc(3 * (size_t)gC + 4);
        int* partl = (int*)alloc(1024);
        int* cur = (int*)alloc(N);

        hipMemsetAsync(deg, 0, N * sizeof(int), stream);
        hipMemsetAsync(cur, 0, N * sizeof(int), stream);

        k_deg<<<gE, B, 0, stream>>>(dst, E, deg);
        k_scan1<<<gN, B, 0, stream>>>(deg, offs, partl, N);
        k_scan2<<<1, 1024, 0, stream>>>(partl, offs, gN, N);
        k_scan3<<<gN, B, 0, stream>>>(offs, partl, N);
        k_fill_cur<<<gE, B, 0, stream>>>(src, dst, offs, cur, col, E);
        k_prescale<<<gN, B, 0, stream>>>(x, offs, bufA, N);
    }

    // convs: G lanes/node, float4 gathers, dinv carried in .w
    k_conv1<<<gC, B, 0, stream>>>(offs, col, bufA, W1, b1, W2, bufB, N);
    k_conv2<<<gC, B, 0, stream>>>(offs, col, bufB, b2, W3, emb_out, bufA, N);
    k_conv3<<<gC, B, 0, stream>>>(offs, col, bufA, b3, Wp, bp, h_out, pool, N);

    k_head<<<1, 256, 0, stream>>>(pool, gC, Wl, bl, out, N);
}

// Round 9
// 134.657 us; speedup vs baseline: 4.7504x; 1.0446x over previous
//
#include <hip/hip_runtime.h>
#include <math.h>

#define N_NODES 100000
#define NB 256          // partition blocks
#define NP 256          // buckets (dst >> 9), 512 nodes per bucket
#define BSH 9           // bucket shift
#define BMASK 511u      // node-in-bucket mask
#define G 8             // lanes per node in conv gathers

// ================= bucket-path CSR build (no global atomics) =================

__global__ void k_hist(const int* __restrict__ dst, int E,
                       int* __restrict__ hist) {
    __shared__ int bin[NP];
    if (threadIdx.x < NP) bin[threadIdx.x] = 0;
    __syncthreads();
    int ngroups = E >> 2;
    int gchunk = (ngroups + NB - 1) / NB;
    int gbeg = blockIdx.x * gchunk;
    int gend = gbeg + gchunk; if (gend > ngroups) gend = ngroups;
    const int4* d4 = (const int4*)dst;
    for (int g = gbeg + threadIdx.x; g < gend; g += 1024) {
        int4 d = d4[g];
        atomicAdd(&bin[d.x >> BSH], 1);
        atomicAdd(&bin[d.y >> BSH], 1);
        atomicAdd(&bin[d.z >> BSH], 1);
        atomicAdd(&bin[d.w >> BSH], 1);
    }
    if (blockIdx.x == 0) {
        for (int e = (ngroups << 2) + threadIdx.x; e < E; e += 1024)
            atomicAdd(&bin[dst[e] >> BSH], 1);
    }
    __syncthreads();
    if (threadIdx.x < NP)
        hist[blockIdx.x * NP + threadIdx.x] = bin[threadIdx.x];
}

__global__ void k_s1(const int* __restrict__ hist, int* __restrict__ base) {
    __shared__ int sh[NP];
    int b = threadIdx.x;
    int s = 0;
    #pragma unroll 8
    for (int k = 0; k < NB; ++k) s += hist[k * NP + b];
    sh[b] = s;
    __syncthreads();
    for (int off = 1; off < NP; off <<= 1) {
        int u = (b >= off) ? sh[b - off] : 0;
        __syncthreads();
        sh[b] += u;
        __syncthreads();
    }
    base[b] = sh[b] - s;
    if (b == NP - 1) base[NP] = sh[b];
}

__global__ void k_s2(int* __restrict__ hist, const int* __restrict__ base) {
    __shared__ int sh[NB];
    int b = blockIdx.x, t = threadIdx.x;
    int v = hist[t * NP + b];
    sh[t] = v;
    __syncthreads();
    for (int off = 1; off < NB; off <<= 1) {
        int u = (t >= off) ? sh[t - off] : 0;
        __syncthreads();
        sh[t] += u;
        __syncthreads();
    }
    hist[t * NP + b] = base[b] + sh[t] - v;
}

__global__ void k_part(const int* __restrict__ src, const int* __restrict__ dst,
                       int E, const int* __restrict__ hist,
                       unsigned int* __restrict__ part) {
    __shared__ int cur[NP];
    if (threadIdx.x < NP)
        cur[threadIdx.x] = hist[blockIdx.x * NP + threadIdx.x];
    __syncthreads();
    int ngroups = E >> 2;
    int gchunk = (ngroups + NB - 1) / NB;
    int gbeg = blockIdx.x * gchunk;
    int gend = gbeg + gchunk; if (gend > ngroups) gend = ngroups;
    const int4* d4 = (const int4*)dst;
    const int4* s4 = (const int4*)src;
    for (int g = gbeg + threadIdx.x; g < gend; g += 1024) {
        int4 d = d4[g];
        int4 s = s4[g];
        int p;
        p = atomicAdd(&cur[d.x >> BSH], 1);
        part[p] = ((unsigned)s.x << BSH) | ((unsigned)d.x & BMASK);
        p = atomicAdd(&cur[d.y >> BSH], 1);
        part[p] = ((unsigned)s.y << BSH) | ((unsigned)d.y & BMASK);
        p = atomicAdd(&cur[d.z >> BSH], 1);
        part[p] = ((unsigned)s.z << BSH) | ((unsigned)d.z & BMASK);
        p = atomicAdd(&cur[d.w >> BSH], 1);
        part[p] = ((unsigned)s.w << BSH) | ((unsigned)d.w & BMASK);
    }
    if (blockIdx.x == 0) {
        for (int e = (ngroups << 2) + threadIdx.x; e < E; e += 1024) {
            int d = dst[e];
            int p = atomicAdd(&cur[d >> BSH], 1);
            part[p] = ((unsigned)src[e] << BSH) | ((unsigned)d & BMASK);
        }
    }
}

__global__ void k_csr(const unsigned int* __restrict__ part, const int* __restrict__ base,
                      const float* __restrict__ x,
                      int* __restrict__ offs,
                      float4* __restrict__ xp4, int* __restrict__ col, int N) {
    __shared__ int cnt[512];
    __shared__ int scn[512];
    __shared__ int cur[512];
    int b = blockIdx.x, t = threadIdx.x;
    int lo = base[b], hi = base[b + 1];
    if (t < 512) cnt[t] = 0;
    __syncthreads();
    for (int e = lo + t; e < hi; e += 1024)
        atomicAdd(&cnt[part[e] & BMASK], 1);
    __syncthreads();
    int v = (t < 512) ? cnt[t] : 0;
    if (t < 512) scn[t] = v;
    __syncthreads();
    for (int off = 1; off < 512; off <<= 1) {
        int u = (t < 512 && t >= off) ? scn[t - off] : 0;
        __syncthreads();
        if (t < 512) scn[t] += u;
        __syncthreads();
    }
    if (t < 512) {
        int pos = lo + scn[t] - v;        // exclusive
        cur[t] = pos;
        int g = (b << BSH) + t;
        if (g < N) {
            offs[g] = pos;
            float di = rsqrtf((float)(v + 1));   // +1 self-loop
            xp4[g] = make_float4(x[3*g] * di, x[3*g+1] * di, x[3*g+2] * di, di);
        }
    }
    if (b == 0 && t == 0) offs[N] = base[(N_NODES + 511) >> BSH];
    __syncthreads();
    for (int e = lo + t; e < hi; e += 1024) {
        unsigned int w = part[e];
        int p = atomicAdd(&cur[w & BMASK], 1);
        col[p] = (int)(w >> BSH);
    }
}

// ================= fallback CSR build (global atomics) ==========

__global__ void k_deg(const int* __restrict__ dst, int E, int* __restrict__ deg) {
    int e = blockIdx.x * blockDim.x + threadIdx.x;
    if (e < E) atomicAdd(&deg[dst[e]], 1);
}

__global__ void k_scan1(const int* __restrict__ deg, int* __restrict__ offs,
                        int* __restrict__ partl, int N) {
    __shared__ int sh[256];
    int i = blockIdx.x * 256 + threadIdx.x;
    int t = threadIdx.x;
    int v = (i < N) ? deg[i] : 0;
    sh[t] = v;
    __syncthreads();
    #pragma unroll
    for (int off = 1; off < 256; off <<= 1) {
        int u = (t >= off) ? sh[t - off] : 0;
        __syncthreads();
        sh[t] += u;
        __syncthreads();
    }
    if (i < N) offs[i] = sh[t] - v;
    if (t == 255) partl[blockIdx.x] = sh[255];
}

__global__ void k_scan2(int* __restrict__ partl, int* __restrict__ offs, int nb, int N) {
    __shared__ int sh[1024];
    int t = threadIdx.x;
    int v = (t < nb) ? partl[t] : 0;
    sh[t] = v;
    __syncthreads();
    #pragma unroll
    for (int off = 1; off < 1024; off <<= 1) {
        int u = (t >= off) ? sh[t - off] : 0;
        __syncthreads();
        sh[t] += u;
        __syncthreads();
    }
    if (t < nb) partl[t] = sh[t] - v;
    if (t == 1023) offs[N] = sh[1023];
}

__global__ void k_scan3(int* __restrict__ offs, const int* __restrict__ partl, int N) {
    int i = blockIdx.x * 256 + threadIdx.x;
    if (i < N) offs[i] += partl[blockIdx.x];
}

__global__ void k_fill_cur(const int* __restrict__ src, const int* __restrict__ dst,
                           const int* __restrict__ offs, int* __restrict__ cur,
                           int* __restrict__ col, int E) {
    int e = blockIdx.x * blockDim.x + threadIdx.x;
    if (e >= E) return;
    int d = dst[e];
    col[offs[d] + atomicAdd(&cur[d], 1)] = src[e];
}

__global__ void k_prescale(const float* __restrict__ x, const int* __restrict__ offs,
                           float4* __restrict__ xp4, int N) {
    int i = blockIdx.x * blockDim.x + threadIdx.x;
    if (i >= N) return;
    int d = offs[i+1] - offs[i];
    float di = rsqrtf((float)(d + 1));
    xp4[i] = make_float4(x[3*i] * di, x[3*i+1] * di, x[3*i+2] * di, di);
}

// ================= convs: G lanes per node, float4 gathers, 4-deep unroll =====

__device__ __forceinline__ void gather_sum(const int* __restrict__ col,
                                           const float4* __restrict__ tab,
                                           int beg, int end, int g,
                                           float& s0, float& s1, float& s2) {
    int k = beg + g;
    for (; k + 3*G < end; k += 4*G) {
        int c0 = col[k], c1 = col[k+G], c2 = col[k+2*G], c3 = col[k+3*G];
        float4 v0 = tab[c0], v1 = tab[c1], v2 = tab[c2], v3 = tab[c3];
        s0 += v0.x; s1 += v0.y; s2 += v0.z;
        s0 += v1.x; s1 += v1.y; s2 += v1.z;
        s0 += v2.x; s1 += v2.y; s2 += v2.z;
        s0 += v3.x; s1 += v3.y; s2 += v3.z;
    }
    for (; k < end; k += G) {
        float4 v = tab[col[k]];
        s0 += v.x; s1 += v.y; s2 += v.z;
    }
}

__global__ void k_conv1(const int* __restrict__ offs, const int* __restrict__ col,
                        const float4* __restrict__ xp4,
                        const float* __restrict__ W1, const float* __restrict__ b1,
                        const float* __restrict__ W2,
                        float4* __restrict__ h2p4, int N) {
    int tid = blockIdx.x * blockDim.x + threadIdx.x;
    int i = tid >> 3, g = tid & (G - 1);
    if (i >= N) return;
    float s0 = 0.f, s1 = 0.f, s2 = 0.f, di = 0.f;
    if (g == 0) {
        float4 self = xp4[i];          // self-loop term (already * di)
        s0 = self.x; s1 = self.y; s2 = self.z; di = self.w;
    }
    gather_sum(col, xp4, offs[i], offs[i+1], g, s0, s1, s2);
    #pragma unroll
    for (int off = G/2; off > 0; off >>= 1) {
        s0 += __shfl_down(s0, off, G);
        s1 += __shfl_down(s1, off, G);
        s2 += __shfl_down(s2, off, G);
    }
    if (g == 0) {
        float g0 = s0 * di, g1 = s1 * di, g2 = s2 * di;   // (Âx)[i]
        float o0 = 0.f, o1 = 0.f, o2 = 0.f;
        #pragma unroll
        for (int j = 0; j < 16; ++j) {
            float t = fmaxf(g0 * W1[j] + g1 * W1[16 + j] + g2 * W1[32 + j] + b1[j], 0.f);
            o0 += t * W2[3*j + 0];
            o1 += t * W2[3*j + 1];
            o2 += t * W2[3*j + 2];
        }
        h2p4[i] = make_float4(o0 * di, o1 * di, o2 * di, di);
    }
}

__global__ void k_conv2(const int* __restrict__ offs, const int* __restrict__ col,
                        const float4* __restrict__ h2p4,
                        const float* __restrict__ b2, const float* __restrict__ W3,
                        float* __restrict__ embed_out, float4* __restrict__ h3p4, int N) {
    int tid = blockIdx.x * blockDim.x + threadIdx.x;
    int i = tid >> 3, g = tid & (G - 1);
    if (i >= N) return;
    float s0 = 0.f, s1 = 0.f, s2 = 0.f, di = 0.f;
    if (g == 0) {
        float4 self = h2p4[i];
        s0 = self.x; s1 = self.y; s2 = self.z; di = self.w;
    }
    gather_sum(col, h2p4, offs[i], offs[i+1], g, s0, s1, s2);
    #pragma unroll
    for (int off = G/2; off > 0; off >>= 1) {
        s0 += __shfl_down(s0, off, G);
        s1 += __shfl_down(s1, off, G);
        s2 += __shfl_down(s2, off, G);
    }
    if (g == 0) {
        float t0 = s0 * di + b2[0];
        float t1 = s1 * di + b2[1];
        float t2 = s2 * di + b2[2];
        float inv = 1.0f / fmaxf(sqrtf(t0*t0 + t1*t1 + t2*t2), 1e-12f);
        float e0 = t0*inv, e1 = t1*inv, e2 = t2*inv;
        embed_out[3*i] = e0; embed_out[3*i+1] = e1; embed_out[3*i+2] = e2;
        h3p4[i] = make_float4((e0*W3[0] + e1*W3[3] + e2*W3[6]) * di,
                              (e0*W3[1] + e1*W3[4] + e2*W3[7]) * di,
                              (e0*W3[2] + e1*W3[5] + e2*W3[8]) * di, di);
    }
}

// conv3: deterministic pool reduction (per-wave LDS slots, no float atomics)
__global__ void k_conv3(const int* __restrict__ offs, const int* __restrict__ col,
                        const float4* __restrict__ h3p4,
                        const float* __restrict__ b3, const float* __restrict__ Wp,
                        const float* __restrict__ bp,
                        float* __restrict__ hout, float* __restrict__ pool, int N) {
    __shared__ float ws[4][3];  // 256 threads = 4 waves
    int tid = blockIdx.x * blockDim.x + threadIdx.x;
    int i = tid >> 3, g = tid & (G - 1);
    float p0 = 0.f, p1 = 0.f, p2 = 0.f;
    if (i < N) {
        float s0 = 0.f, s1 = 0.f, s2 = 0.f, di = 0.f;
        if (g == 0) {
            float4 self = h3p4[i];
            s0 = self.x; s1 = self.y; s2 = self.z; di = self.w;
        }
        gather_sum(col, h3p4, offs[i], offs[i+1], g, s0, s1, s2);
        #pragma unroll
        for (int off = G/2; off > 0; off >>= 1) {
            s0 += __shfl_down(s0, off, G);
            s1 += __shfl_down(s1, off, G);
            s2 += __shfl_down(s2, off, G);
        }
        if (g == 0) {
            float t0 = s0 * di + b3[0];
            float t1 = s1 * di + b3[1];
            float t2 = s2 * di + b3[2];
            p0 = t0*Wp[0] + t1*Wp[3] + t2*Wp[6] + bp[0];
            p1 = t0*Wp[1] + t1*Wp[4] + t2*Wp[7] + bp[1];
            p2 = t0*Wp[2] + t1*Wp[5] + t2*Wp[8] + bp[2];
            hout[3*i] = p0; hout[3*i+1] = p1; hout[3*i+2] = p2;
        }
    }
    // wave reduce (only g==0 lanes nonzero), per-wave slot, serial block sum
    #pragma unroll
    for (int off = 32; off > 0; off >>= 1) {
        p0 += __shfl_down(p0, off);
        p1 += __shfl_down(p1, off);
        p2 += __shfl_down(p2, off);
    }
    if ((threadIdx.x & 63) == 0) {
        int w = threadIdx.x >> 6;
        ws[w][0] = p0; ws[w][1] = p1; ws[w][2] = p2;
    }
    __syncthreads();
    if (threadIdx.x == 0) {
        pool[3*blockIdx.x]   = ws[0][0] + ws[1][0] + ws[2][0] + ws[3][0];
        pool[3*blockIdx.x+1] = ws[0][1] + ws[1][1] + ws[2][1] + ws[3][1];
        pool[3*blockIdx.x+2] = ws[0][2] + ws[1][2] + ws[2][2] + ws[3][2];
    }
}

// head: deterministic reduce of block partials, then logits + log_softmax
__global__ void k_head(const float* __restrict__ pool, int nb,
                       const float* __restrict__ Wl, const float* __restrict__ bl,
                       float* __restrict__ out, int N) {
    __shared__ float sh[12];  // 4 waves x 3
    int t = threadIdx.x;
    float p0 = 0.f, p1 = 0.f, p2 = 0.f;
    for (int k = t; k < nb; k += 256) {
        p0 += pool[3*k]; p1 += pool[3*k+1]; p2 += pool[3*k+2];
    }
    #pragma unroll
    for (int off = 32; off > 0; off >>= 1) {
        p0 += __shfl_down(p0, off);
        p1 += __shfl_down(p1, off);
        p2 += __shfl_down(p2, off);
    }
    if ((t & 63) == 0) {
        int w = t >> 6;
        sh[3*w] = p0; sh[3*w+1] = p1; sh[3*w+2] = p2;
    }
    __syncthreads();
    if (t == 0) {
        p0 = sh[0] + sh[3] + sh[6] + sh[9];
        p1 = sh[1] + sh[4] + sh[7] + sh[10];
        p2 = sh[2] + sh[5] + sh[8] + sh[11];
        p0 /= (float)N; p1 /= (float)N; p2 /= (float)N;
        float l[10];
        float m = -1e30f;
        #pragma unroll
        for (int j = 0; j < 10; ++j) {
            l[j] = p0 * Wl[j] + p1 * Wl[10 + j] + p2 * Wl[20 + j] + bl[j];
            m = fmaxf(m, l[j]);
        }
        float s = 0.f;
        #pragma unroll
        for (int j = 0; j < 10; ++j) s += expf(l[j] - m);
        float lse = logf(s) + m;
        #pragma unroll
        for (int j = 0; j < 10; ++j) out[j] = l[j] - lse;
    }
}

extern "C" void kernel_launch(void* const* d_in, const int* in_sizes, int n_in,
                              void* d_out, int out_size, void* d_ws, size_t ws_size,
                              hipStream_t stream) {
    const int N = N_NODES;
    const float* x  = (const float*)d_in[0];
    const int*   ei = (const int*)d_in[1];
    const int    E  = in_sizes[1] / 2;
    const int* src = ei;
    const int* dst = ei + E;
    const float* W1 = (const float*)d_in[2];
    const float* b1 = (const float*)d_in[3];
    const float* W2 = (const float*)d_in[4];
    const float* b2 = (const float*)d_in[5];
    const float* W3 = (const float*)d_in[6];
    const float* b3 = (const float*)d_in[7];
    const float* Wp = (const float*)d_in[8];
    const float* bp = (const float*)d_in[9];
    const float* Wl = (const float*)d_in[10];
    const float* bl = (const float*)d_in[11];

    float* out     = (float*)d_out;
    float* h_out   = out + 10;              // [N,3]
    float* emb_out = out + 10 + 3 * N;      // [N,3]

    const int B = 256;
    int gE = (E + B - 1) / B;
    int gN = (N + B - 1) / B;
    int gC = ((size_t)N * G + B - 1) / B;   // conv grid (3125 blocks)
    int PB = (N + 511) >> BSH;              // 196 buckets

    char* Wm = (char*)d_ws;

    // ---- bucket-path layout ----
    size_t off = 0;
    auto alloc = [&](size_t elems) { void* p = Wm + off; off += elems * 4; return p; };
    int*          col  = (int*)alloc((size_t)E);
    unsigned int* part = (unsigned int*)alloc((size_t)E);
    int*          hist = (int*)alloc((size_t)NB * NP);
    int*          base = (int*)alloc(NP + 1);
    int*          offs = (int*)alloc(N + 1);
    float4*       bufA = (float4*)alloc(4 * N);
    float4*       bufB = (float4*)alloc(4 * N);
    float*        pool = (float*)alloc(3 * (size_t)gC + 4);
    size_t need_bucket = off;

    if (ws_size >= need_bucket) {
        k_hist<<<NB, 1024, 0, stream>>>(dst, E, hist);
        k_s1<<<1, NP, 0, stream>>>(hist, base);
        k_s2<<<NP, NB, 0, stream>>>(hist, base);
        k_part<<<NB, 1024, 0, stream>>>(src, dst, E, hist, part);
        k_csr<<<PB, 1024, 0, stream>>>(part, base, x, offs, bufA, col, N);
    } else {
        // ---- fallback layout ----
        off = 0;
        col  = (int*)alloc((size_t)E);
        int* deg = (int*)alloc(N);
        offs = (int*)alloc(N + 1);
        bufA = (float4*)alloc(4 * N);
        bufB = (float4*)alloc(4 * N);
        pool = (float*)alloc(3 * (size_t)gC + 4);
        int* partl = (int*)alloc(1024);
        int* cur = (int*)alloc(N);

        hipMemsetAsync(deg, 0, N * sizeof(int), stream);
        hipMemsetAsync(cur, 0, N * sizeof(int), stream);

        k_deg<<<gE, B, 0, stream>>>(dst, E, deg);
        k_scan1<<<gN, B, 0, stream>>>(deg, offs, partl, N);
        k_scan2<<<1, 1024, 0, stream>>>(partl, offs, gN, N);
        k_scan3<<<gN, B, 0, stream>>>(offs, partl, N);
        k_fill_cur<<<gE, B, 0, stream>>>(src, dst, offs, cur, col, E);
        k_prescale<<<gN, B, 0, stream>>>(x, offs, bufA, N);
    }

    // convs: G lanes/node, float4 gathers, dinv carried in .w
    k_conv1<<<gC, B, 0, stream>>>(offs, col, bufA, W1, b1, W2, bufB, N);
    k_conv2<<<gC, B, 0, stream>>>(offs, col, bufB, b2, W3, emb_out, bufA, N);
    k_conv3<<<gC, B, 0, stream>>>(offs, col, bufA, b3, Wp, bp, h_out, pool, N);

    k_head<<<1, 256, 0, stream>>>(pool, gC, Wl, bl, out, N);
}